// Round 1
// baseline (198.600 us; speedup 1.0000x reference)
//
#include <hip/hip_runtime.h>

// Problem constants (from reference setup_inputs)
#define B 8
#define C 64
#define H 152
#define W 272
#define HW (H * W)          // 41344
#define K 500
#define ALPHA 0.25f
#define PROB_MIN 1e-4f

#define TS 32               // tile size in i and j
#define NT ((K + TS - 1) / TS)   // 16 tiles per dim
#define LDS_PAD 68          // 64 + 4 pad: float4-aligned, <=2-way bank conflict

// ---------------------------------------------------------------------------
// Kernel 1: masked gather  cur_feat/pre_feat[b,k,c] = reid[b, c, idx(b,k)]
// Also zero-initializes the scalar output (it is poisoned 0xAA before replay).
// ---------------------------------------------------------------------------
__global__ __launch_bounds__(128) void gather_kernel(
    const float* __restrict__ cur_reid,
    const float* __restrict__ pre_reid,
    const int* __restrict__ cur_inds,
    const int* __restrict__ pre_inds,
    const int* __restrict__ cur_circ,
    const int* __restrict__ pre_circ,
    const int* __restrict__ tmask,
    float* __restrict__ curf,
    float* __restrict__ pref,
    float* __restrict__ out)
{
    const int bk = blockIdx.x;      // 0 .. B*K-1
    const int t  = threadIdx.x;     // 0 .. 127
    if (bk == 0 && t == 0) out[0] = 0.0f;  // runs before loss kernel (stream order)

    const int b = bk / K;
    const int m = tmask[bk];        // tracking_mask[b,k,0] in {0,1}
    if (t < C) {
        const int idx = m ? cur_inds[bk] : cur_circ[bk];
        curf[(size_t)bk * C + t] = cur_reid[((size_t)(b * C + t)) * HW + idx];
    } else {
        const int c = t - C;
        const int idx = m ? pre_inds[bk] : pre_circ[bk];
        pref[(size_t)bk * C + c] = pre_reid[((size_t)(b * C + c)) * HW + idx];
    }
}

// ---------------------------------------------------------------------------
// Kernel 2: sim = sigmoid(cur_feat @ pre_feat^T), focal loss, mean-reduce.
// 32x32 tile per block, 256 threads (16x16), 2x2 outputs per thread.
// ---------------------------------------------------------------------------
__device__ __forceinline__ float focal_term(float x, int gi, int gj, int b,
                                            const int* __restrict__ tmask)
{
    if (gi >= K || gj >= K) return 0.0f;
    const float sim = 1.0f / (1.0f + __expf(-x));
    const int gt = (gi == gj) ? tmask[b * K + gi] : 0;
    float p = gt ? sim : 1.0f - sim;
    p = fminf(fmaxf(p, PROB_MIN), 1.0f);
    const float a = gt ? ALPHA : (1.0f - ALPHA);
    const float om = 1.0f - p;
    return a * om * om * (-__logf(p));
}

__global__ __launch_bounds__(256) void loss_kernel(
    const float* __restrict__ curf,
    const float* __restrict__ pref,
    const int* __restrict__ tmask,
    float* __restrict__ out)
{
    __shared__ float sc[TS][LDS_PAD];
    __shared__ float sp[TS][LDS_PAD];
    __shared__ float wsum[4];

    const int ti = blockIdx.x;
    const int tj = blockIdx.y;
    const int b  = blockIdx.z;
    const int t  = threadIdx.x;
    const int i0 = ti * TS;
    const int j0 = tj * TS;

    // Stage tiles: 32 rows x 16 float4 per tile = 512 float4; 2 per thread.
#pragma unroll
    for (int r = 0; r < 2; ++r) {
        const int f   = t + r * 256;
        const int row = f >> 4;
        const int c4  = (f & 15) * 4;
        float4 va = make_float4(0.f, 0.f, 0.f, 0.f);
        float4 vb = make_float4(0.f, 0.f, 0.f, 0.f);
        const int gi = i0 + row;
        const int gj = j0 + row;
        if (gi < K) va = *(const float4*)&curf[((size_t)(b * K + gi)) * C + c4];
        if (gj < K) vb = *(const float4*)&pref[((size_t)(b * K + gj)) * C + c4];
        *(float4*)&sc[row][c4] = va;
        *(float4*)&sp[row][c4] = vb;
    }
    __syncthreads();

    const int tx = t & 15;
    const int ty = t >> 4;
    float a00 = 0.f, a01 = 0.f, a10 = 0.f, a11 = 0.f;

#pragma unroll
    for (int c = 0; c < C; c += 4) {
        const float4 x0 = *(const float4*)&sc[ty][c];
        const float4 x1 = *(const float4*)&sc[ty + 16][c];
        const float4 y0 = *(const float4*)&sp[tx][c];
        const float4 y1 = *(const float4*)&sp[tx + 16][c];
        a00 += x0.x * y0.x + x0.y * y0.y + x0.z * y0.z + x0.w * y0.w;
        a01 += x0.x * y1.x + x0.y * y1.y + x0.z * y1.z + x0.w * y1.w;
        a10 += x1.x * y0.x + x1.y * y0.y + x1.z * y0.z + x1.w * y0.w;
        a11 += x1.x * y1.x + x1.y * y1.y + x1.z * y1.z + x1.w * y1.w;
    }

    const int gi0 = i0 + ty, gi1 = i0 + ty + 16;
    const int gj0 = j0 + tx, gj1 = j0 + tx + 16;
    float s = focal_term(a00, gi0, gj0, b, tmask)
            + focal_term(a01, gi0, gj1, b, tmask)
            + focal_term(a10, gi1, gj0, b, tmask)
            + focal_term(a11, gi1, gj1, b, tmask);

    // Block reduction: wave64 shuffle, then 4 wave partials via LDS.
#pragma unroll
    for (int o = 32; o > 0; o >>= 1) s += __shfl_down(s, o, 64);
    if ((t & 63) == 0) wsum[t >> 6] = s;
    __syncthreads();
    if (t == 0) {
        const float tot = wsum[0] + wsum[1] + wsum[2] + wsum[3];
        atomicAdd(out, tot * (1.0f / ((float)B * (float)K * (float)K)));
    }
}

// ---------------------------------------------------------------------------
extern "C" void kernel_launch(void* const* d_in, const int* in_sizes, int n_in,
                              void* d_out, int out_size, void* d_ws, size_t ws_size,
                              hipStream_t stream)
{
    const float* cur_reid = (const float*)d_in[0];
    const float* pre_reid = (const float*)d_in[1];
    const int*   cur_inds = (const int*)d_in[2];
    const int*   pre_inds = (const int*)d_in[3];
    const int*   cur_circ = (const int*)d_in[4];
    const int*   pre_circ = (const int*)d_in[5];
    const int*   tmask    = (const int*)d_in[6];
    float*       out      = (float*)d_out;

    float* curf = (float*)d_ws;                        // B*K*C floats = 1.024 MB
    float* pref = curf + (size_t)B * K * C;            // another 1.024 MB

    gather_kernel<<<B * K, 128, 0, stream>>>(
        cur_reid, pre_reid, cur_inds, pre_inds, cur_circ, pre_circ, tmask,
        curf, pref, out);

    dim3 grid(NT, NT, B);
    loss_kernel<<<grid, 256, 0, stream>>>(curf, pref, tmask, out);
}

// Round 2
// 176.403 us; speedup vs baseline: 1.1258x; 1.1258x over previous
//
#include <hip/hip_runtime.h>

// Problem constants (from reference setup_inputs)
#define B 8
#define C 64
#define H 152
#define W 272
#define HW (H * W)          // 41344
#define K 500
#define KP 512              // K padded to tile multiple
#define ALPHA 0.25f
#define PROB_MIN 1e-4f

typedef __attribute__((ext_vector_type(8))) short short8;   // 8 bf16 (4 VGPRs)
typedef __attribute__((ext_vector_type(4))) float floatx4;  // 4 fp32 acc

// fp32 -> bf16 round-to-nearest-even
__device__ __forceinline__ unsigned short f32_to_bf16(float f) {
    union { float f; unsigned int u; } v; v.f = f;
    unsigned int r = v.u + 0x7FFFu + ((v.u >> 16) & 1u);
    return (unsigned short)(r >> 16);
}

// ---------------------------------------------------------------------------
// Kernel 1: masked gather -> bf16 feats [B, KP, C]; zero-pads rows K..KP-1.
// Also zero-initializes the scalar output (poisoned 0xAA before replay).
// ---------------------------------------------------------------------------
__global__ __launch_bounds__(128) void gather_kernel(
    const float* __restrict__ cur_reid,
    const float* __restrict__ pre_reid,
    const int* __restrict__ cur_inds,
    const int* __restrict__ pre_inds,
    const int* __restrict__ cur_circ,
    const int* __restrict__ pre_circ,
    const int* __restrict__ tmask,
    unsigned short* __restrict__ curf,
    unsigned short* __restrict__ pref,
    float* __restrict__ out)
{
    const int bk = blockIdx.x;          // 0 .. B*KP-1
    const int t  = threadIdx.x;         // 0 .. 127
    if (bk == 0 && t == 0) out[0] = 0.0f;  // before loss kernel (stream order)

    const int b = bk >> 9;              // /KP
    const int k = bk & (KP - 1);

    if (k >= K) {                       // padding rows -> zero
        if (t < C)      curf[(size_t)bk * C + t] = 0;
        else            pref[(size_t)bk * C + (t - C)] = 0;
        return;
    }

    const int bk_in = b * K + k;        // index into [B,K] arrays
    const int m = tmask[bk_in];
    if (t < C) {
        const int idx = m ? cur_inds[bk_in] : cur_circ[bk_in];
        const float v = cur_reid[((size_t)(b * C + t)) * HW + idx];
        curf[(size_t)bk * C + t] = f32_to_bf16(v);
    } else {
        const int c = t - C;
        const int idx = m ? pre_inds[bk_in] : pre_circ[bk_in];
        const float v = pre_reid[((size_t)(b * C + c)) * HW + idx];
        pref[(size_t)bk * C + c] = f32_to_bf16(v);
    }
}

// ---------------------------------------------------------------------------
// Kernel 2: per-wave 16x16 tile of sim via MFMA 16x16x32 bf16 (2 MFMAs, K=64),
// fragments loaded directly from global (feat fits in L1/L2), fused focal
// loss + block reduce + one atomicAdd per block.
// ---------------------------------------------------------------------------
__device__ __forceinline__ float focal_term(float x, int gi, int gj, int b,
                                            const int* __restrict__ tmask)
{
    if (gi >= K || gj >= K) return 0.0f;
    const float sim = 1.0f / (1.0f + __expf(-x));
    const int gt = (gi == gj) ? tmask[b * K + gi] : 0;
    float p = gt ? sim : 1.0f - sim;
    p = fminf(fmaxf(p, PROB_MIN), 1.0f);
    const float a = gt ? ALPHA : (1.0f - ALPHA);
    const float om = 1.0f - p;
    return a * om * om * (-__logf(p));
}

#define LOSS_THREADS 1024   // 16 waves per block -> 16 tiles per block

__global__ __launch_bounds__(LOSS_THREADS) void loss_kernel(
    const unsigned short* __restrict__ curf,
    const unsigned short* __restrict__ pref,
    const int* __restrict__ tmask,
    float* __restrict__ out)
{
    __shared__ float wsum[LOSS_THREADS / 64];

    const int t    = threadIdx.x;
    const int wave = t >> 6;
    const int lane = t & 63;

    // Flat tile id -> (b, ti, tj); tiles: 32 x 32 per batch, 8 batches = 8192.
    const int tile = blockIdx.x * (LOSS_THREADS / 64) + wave;
    const int b    = tile >> 10;
    const int rem  = tile & 1023;
    const int ti   = rem >> 5;
    const int tj   = rem & 31;

    const int m16  = lane & 15;   // A-row / B-row (=sim col) within tile
    const int quad = lane >> 4;   // 0..3

    // A frag: curf[b][ti*16 + m16][quad*8 + (0..7)]  (+32 for second MFMA)
    const unsigned short* pa = curf + (((size_t)(b * KP + ti * 16 + m16)) * C + quad * 8);
    const unsigned short* pb = pref + (((size_t)(b * KP + tj * 16 + m16)) * C + quad * 8);
    const short8 a0 = *(const short8*)pa;
    const short8 a1 = *(const short8*)(pa + 32);
    const short8 b0 = *(const short8*)pb;
    const short8 b1 = *(const short8*)(pb + 32);

    floatx4 acc = {0.f, 0.f, 0.f, 0.f};
    acc = __builtin_amdgcn_mfma_f32_16x16x32_bf16(a0, b0, acc, 0, 0, 0);
    acc = __builtin_amdgcn_mfma_f32_16x16x32_bf16(a1, b1, acc, 0, 0, 0);

    // C/D layout: col = lane&15, row = quad*4 + reg   [measured m89/m91]
    const int gj = tj * 16 + m16;
    float s = 0.f;
#pragma unroll
    for (int r = 0; r < 4; ++r) {
        const int gi = ti * 16 + quad * 4 + r;
        s += focal_term(acc[r], gi, gj, b, tmask);
    }

    // wave64 butterfly, then cross-wave via LDS, one atomic per block
#pragma unroll
    for (int o = 32; o > 0; o >>= 1) s += __shfl_down(s, o, 64);
    if (lane == 0) wsum[wave] = s;
    __syncthreads();
    if (t == 0) {
        float tot = 0.f;
#pragma unroll
        for (int w = 0; w < LOSS_THREADS / 64; ++w) tot += wsum[w];
        atomicAdd(out, tot * (1.0f / ((float)B * (float)K * (float)K)));
    }
}

// ---------------------------------------------------------------------------
extern "C" void kernel_launch(void* const* d_in, const int* in_sizes, int n_in,
                              void* d_out, int out_size, void* d_ws, size_t ws_size,
                              hipStream_t stream)
{
    const float* cur_reid = (const float*)d_in[0];
    const float* pre_reid = (const float*)d_in[1];
    const int*   cur_inds = (const int*)d_in[2];
    const int*   pre_inds = (const int*)d_in[3];
    const int*   cur_circ = (const int*)d_in[4];
    const int*   pre_circ = (const int*)d_in[5];
    const int*   tmask    = (const int*)d_in[6];
    float*       out      = (float*)d_out;

    unsigned short* curf = (unsigned short*)d_ws;            // B*KP*C bf16 = 512 KB
    unsigned short* pref = curf + (size_t)B * KP * C;        // another 512 KB

    gather_kernel<<<B * KP, 128, 0, stream>>>(
        cur_reid, pre_reid, cur_inds, pre_inds, cur_circ, pre_circ, tmask,
        curf, pref, out);

    // 8192 tiles (32x32x8) / 16 waves per block = 512 blocks
    loss_kernel<<<512, LOSS_THREADS, 0, stream>>>(curf, pref, tmask, out);
}